// Round 7
// baseline (169.612 us; speedup 1.0000x reference)
//
#include <hip/hip_runtime.h>
#include <hip/hip_bf16.h>
#include <hip/hip_fp16.h>
#include <math.h>

typedef _Float16 f16x8 __attribute__((ext_vector_type(8)));
typedef _Float16 h2 __attribute__((ext_vector_type(2)));
typedef __fp16 h2amd __attribute__((ext_vector_type(2)));   // builtin return type
typedef float f32x16 __attribute__((ext_vector_type(16)));
typedef float f32x2 __attribute__((ext_vector_type(2)));

#define DH 100      // hidden dim
#define G  4096     // table size per net
#define WSTR 120    // LDS row stride in f16 elems
#define NBLK 64     // 64 blocks <= 256 CUs => co-residency by capacity alone

// ws float offsets
#define WS_CCW   0      // [0,101)
#define WS_XSC   128    // [128,229)
#define WS_OH0   256    // 3
#define WS_EOH1  260    // 3
#define WS_RNG   800    // net-2 {u0, dlt, inv} at [808,811)
#define WS_BAR   960    // ints: cnt[0..3] @ +0, flags @ +32 (separate lines)
#define WS_TAB   17408  // 3*G table floats

__device__ __forceinline__ unsigned short f2bf(float f) {
    unsigned int u = __float_as_uint(f);
    unsigned int r = (u + 0x7FFFu + ((u >> 16) & 1u)) >> 16;  // RNE
    return (unsigned short)r;
}
__device__ __forceinline__ unsigned int hpk(float a, float b) {
    union { h2amd h; unsigned int u; } c;
    c.h = __builtin_amdgcn_cvt_pkrtz(a, b);
    return c.u;
}
__device__ __forceinline__ h2 hpk2(float a, float b) {
    union { h2amd ha; h2 h; } c;
    c.ha = __builtin_amdgcn_cvt_pkrtz(a, b);
    return c.h;
}

// grid barrier (R6-verified): relaxed add; last arriver stores a release flag
// on a separate cacheline; others poll it with relaxed loads. One release
// fence before arrival, one acquire fence after exit, per block.
// Deadlock-free (grid <= CU count); replay-safe (stale state falls through).
__device__ __forceinline__ void gridbar(int* bar, int idx) {
    __syncthreads();
    if (threadIdx.x == 0) {
        __threadfence();   // release
        int old = __hip_atomic_fetch_add(&bar[idx], 1, __ATOMIC_RELAXED,
                                         __HIP_MEMORY_SCOPE_AGENT);
        if (old == NBLK - 1) {
            __hip_atomic_store(&bar[32 + idx], 1, __ATOMIC_RELAXED,
                               __HIP_MEMORY_SCOPE_AGENT);
        } else {
            while (__hip_atomic_load(&bar[32 + idx], __ATOMIC_RELAXED,
                                     __HIP_MEMORY_SCOPE_AGENT) == 0)
                __builtin_amdgcn_s_sleep(4);
        }
        __threadfence();   // acquire
    }
    __syncthreads();
}

union FR { f16x8 v; h2 h[4]; unsigned int u32[4]; };

// phase-overlaid LDS (max member ~49.8 KB)
union MegaSh {
    struct { float hw[DH * 101]; float bufA[128]; float bufB[128]; } prep;
    struct {
        __align__(16) _Float16 W1[DH * WSTR];
        __align__(16) _Float16 W2[DH * WSTR];
        unsigned int w0p[64], b0p[64], w3p[64];
        float g[256];
    } mlp;
    struct { __align__(16) float tab[3 * G]; } ev;
};

// verified transposed MFMA dataflow (lane^32 exchange, laundered LDS reads):
// evaluates g(u)=elu(MLP(u))+1 for two 128-row groups; dzout valid on !hfb.
__device__ __forceinline__ void mlp2(const _Float16* __restrict__ W1s,
                                     const _Float16* __restrict__ W2s,
                                     const unsigned int* __restrict__ w0p_s,
                                     const unsigned int* __restrict__ b0p_s,
                                     const unsigned int* __restrict__ w3p_s,
                                     const h2* uu, const int* wrow,
                                     const int hf, const bool hfb,
                                     const float b3, unsigned int zoff,
                                     float* dzout)
{
    const f32x2 zero2 = {0.f, 0.f};

    FR a1[2][7];
    #pragma unroll
    for (int ks = 0; ks < 7; ++ks) {
        int pb = ks * 8 + hf * 4 + zoff;
        uint4 wq = *(const uint4*)&w0p_s[pb];
        uint4 bq = *(const uint4*)&b0p_s[pb];
        unsigned int wqa[4] = {wq.x, wq.y, wq.z, wq.w};
        unsigned int bqa[4] = {bq.x, bq.y, bq.z, bq.w};
        #pragma unroll
        for (int i = 0; i < 4; ++i) {
            union { unsigned int u; h2 h; } cw, cb;
            cw.u = wqa[i]; cb.u = bqa[i];
            h2 z = {(_Float16)0.f, (_Float16)0.f};
            #pragma unroll
            for (int j = 0; j < 2; ++j) {
                h2 r = __builtin_elementwise_fma(uu[j], cw.h, cb.h);
                a1[j][ks].h[i] = __builtin_elementwise_max(r, z);
            }
        }
    }

    FR f3[2][7];
    #pragma unroll
    for (int nt = 0; nt < 4; ++nt) {
        f32x16 acc[2];
        #pragma unroll
        for (int r = 0; r < 16; ++r) { acc[0][r] = 0.f; acc[1][r] = 0.f; }
        #pragma unroll
        for (int ks = 0; ks < 7; ++ks) {
            f16x8 wA = *(const f16x8*)&W1s[wrow[nt] + ks * 16 + zoff];
            acc[0] = __builtin_amdgcn_mfma_f32_32x32x16_f16(wA, a1[0][ks].v, acc[0], 0, 0, 0);
            acc[1] = __builtin_amdgcn_mfma_f32_32x32x16_f16(wA, a1[1][ks].v, acc[1], 0, 0, 0);
        }
        #pragma unroll
        for (int j = 0; j < 2; ++j) {
            if (nt < 3) {
                unsigned int pk[4][2];
                #pragma unroll
                for (int qi = 0; qi < 4; ++qi) {
                    f32x2 lo = {acc[j][4 * qi + 0], acc[j][4 * qi + 1]};
                    f32x2 hi = {acc[j][4 * qi + 2], acc[j][4 * qi + 3]};
                    lo = __builtin_elementwise_max(lo, zero2);
                    hi = __builtin_elementwise_max(hi, zero2);
                    pk[qi][0] = hpk(lo[0], lo[1]);
                    pk[qi][1] = hpk(hi[0], hi[1]);
                }
                #pragma unroll
                for (int kk = 0; kk < 2; ++kk) {
                    unsigned int X0 = hfb ? pk[2 * kk][0] : pk[2 * kk + 1][0];
                    unsigned int X1 = hfb ? pk[2 * kk][1] : pk[2 * kk + 1][1];
                    unsigned int O0 = hfb ? pk[2 * kk + 1][0] : pk[2 * kk][0];
                    unsigned int O1 = hfb ? pk[2 * kk + 1][1] : pk[2 * kk][1];
                    unsigned int Y0 = (unsigned int)__shfl_xor((int)X0, 32, 64);
                    unsigned int Y1 = (unsigned int)__shfl_xor((int)X1, 32, 64);
                    f3[j][nt * 2 + kk].u32[0] = hfb ? Y0 : O0;
                    f3[j][nt * 2 + kk].u32[1] = hfb ? Y1 : O1;
                    f3[j][nt * 2 + kk].u32[2] = hfb ? O0 : Y0;
                    f3[j][nt * 2 + kk].u32[3] = hfb ? O1 : Y1;
                }
            } else {
                f32x2 lo = {acc[j][0], acc[j][1]};
                f32x2 hi = {acc[j][2], acc[j][3]};
                lo = __builtin_elementwise_max(lo, zero2);
                hi = __builtin_elementwise_max(hi, zero2);
                unsigned int p0 = hpk(lo[0], lo[1]);
                unsigned int p1 = hpk(hi[0], hi[1]);
                f3[j][6].u32[0] = hfb ? 0u : p0;
                f3[j][6].u32[1] = hfb ? 0u : p1;
                f3[j][6].u32[2] = hfb ? 0u : 0x00003C00u;   // f16 1.0 (bias slot)
                f3[j][6].u32[3] = 0u;
            }
        }
    }

    f32x2 oacc2[2] = {{0.f, 0.f}, {0.f, 0.f}};
    #pragma unroll
    for (int nt2 = 0; nt2 < 4; ++nt2) {
        f32x16 acc2[2];
        #pragma unroll
        for (int r = 0; r < 16; ++r) { acc2[0][r] = 0.f; acc2[1][r] = 0.f; }
        #pragma unroll
        for (int ks = 0; ks < 7; ++ks) {
            f16x8 wA = *(const f16x8*)&W2s[wrow[nt2] + ks * 16 + zoff];
            acc2[0] = __builtin_amdgcn_mfma_f32_32x32x16_f16(wA, f3[0][ks].v, acc2[0], 0, 0, 0);
            acc2[1] = __builtin_amdgcn_mfma_f32_32x32x16_f16(wA, f3[1][ks].v, acc2[1], 0, 0, 0);
        }
        uint4 wa = *(const uint4*)&w3p_s[hf * 32 + nt2 * 8 + zoff];
        uint4 wb2 = *(const uint4*)&w3p_s[hf * 32 + nt2 * 8 + 4 + zoff];
        unsigned int w8[8] = {wa.x, wa.y, wa.z, wa.w, wb2.x, wb2.y, wb2.z, wb2.w};
        f32x2 w3v[8];
        #pragma unroll
        for (int q = 0; q < 8; ++q) {
            w3v[q][0] = __uint_as_float(w8[q] << 16);
            w3v[q][1] = __uint_as_float(w8[q] & 0xFFFF0000u);
        }
        #pragma unroll
        for (int j = 0; j < 2; ++j)
            #pragma unroll
            for (int qi = 0; qi < 4; ++qi) {
                f32x2 lo = {acc2[j][4 * qi + 0], acc2[j][4 * qi + 1]};
                f32x2 hi = {acc2[j][4 * qi + 2], acc2[j][4 * qi + 3]};
                lo = __builtin_elementwise_max(lo, zero2);
                hi = __builtin_elementwise_max(hi, zero2);
                oacc2[j] = __builtin_elementwise_fma(lo, w3v[qi * 2], oacc2[j]);
                oacc2[j] = __builtin_elementwise_fma(hi, w3v[qi * 2 + 1], oacc2[j]);
            }
    }

    #pragma unroll
    for (int j = 0; j < 2; ++j) {
        float oacc = oacc2[j][0] + oacc2[j][1];
        float o = oacc + __shfl_xor(oacc, 32, 64) + b3;
        dzout[j] = (o > 0.f) ? (o + 1.f) : expf(o);   // elu(o) + 1
    }
}

// weight staging for one net into sh.mlp (verified block)
__device__ __forceinline__ void stage_net(MegaSh& sh, int kk, int tid,
                                          const float* __restrict__ iW0,
                                          const float* __restrict__ ib0,
                                          const float* __restrict__ iW1,
                                          const float* __restrict__ ib1,
                                          const float* __restrict__ iW2,
                                          const float* __restrict__ ib2,
                                          const float* __restrict__ iW3)
{
    if (tid < 64) {
        int s0 = 2 * tid, s1 = 2 * tid + 1;
        float w0a = (s0 < DH) ? iW0[(kk * DH + s0) * 3] : 0.f;   // h==0: feature 0 only
        float w0b = (s1 < DH) ? iW0[(kk * DH + s1) * 3] : 0.f;
        float b0a = (s0 < DH) ? ib0[kk * DH + s0] : ((s0 == DH) ? 1.f : 0.f);
        float b0b = (s1 < DH) ? ib0[kk * DH + s1] : 0.f;
        sh.mlp.w0p[tid] = hpk(w0a, w0b);
        sh.mlp.b0p[tid] = hpk(b0a, b0b);

        int hf_i = tid >> 5, rem = tid & 31;
        int nt2 = rem >> 3, qq = (rem >> 1) & 3, pr = rem & 1;
        int n2e = 32 * nt2 + 8 * qq + 2 * pr + 4 * hf_i;
        float we = (n2e < DH) ? iW3[kk * DH + n2e] : 0.f;
        float wo = (n2e + 1 < DH) ? iW3[kk * DH + n2e + 1] : 0.f;
        sh.mlp.w3p[tid] = ((unsigned int)f2bf(wo) << 16) | (unsigned int)f2bf(we);
    }
    const float* W1g = iW1 + (size_t)kk * DH * DH;
    const float* W2g = iW2 + (size_t)kk * DH * DH;
    for (int i = tid; i < DH * WSTR; i += 256) {
        int r = i / WSTR, c = i - r * WSTR;
        float v1, v2;
        if (c < DH)       { v1 = W1g[r * DH + c]; v2 = W2g[r * DH + c]; }
        else if (c == DH) { v1 = ib1[kk * DH + r]; v2 = ib2[kk * DH + r]; }
        else              { v1 = 0.f; v2 = 0.f; }
        sh.mlp.W1[r * WSTR + c] = (_Float16)v1;
        sh.mlp.W2[r * WSTR + c] = (_Float16)v2;
    }
}

// h-MLP for one net using sh.prep; publishes o0 -> ws[WS_OH0+k],
// e1 -> ws[WS_EOH1+k], and optionally LDS copies.
__device__ __forceinline__ void hmlp(MegaSh& sh, int k, int tid,
                                     const float* __restrict__ hb0,
                                     const float* __restrict__ hW1,
                                     const float* __restrict__ hb1,
                                     const float* __restrict__ hW2,
                                     const float* __restrict__ hb2,
                                     const float* __restrict__ hW3,
                                     const float* __restrict__ hb3,
                                     float* __restrict__ ws,
                                     float* o0e1_s)
{
    if (tid < 128) sh.prep.bufA[tid] = (tid < DH) ? fmaxf(hb0[k * DH + tid], 0.f) : 0.f;
    __syncthreads();
    for (int i = tid; i < DH * DH; i += 256) {
        int r = i / DH, c = i - r * DH;
        sh.prep.hw[r * 101 + c] = hW1[k * DH * DH + i];
    }
    __syncthreads();
    if (tid < DH) {
        float acc = hb1[k * DH + tid];
        for (int i = 0; i < DH; ++i) acc = fmaf(sh.prep.hw[tid * 101 + i], sh.prep.bufA[i], acc);
        sh.prep.bufB[tid] = fmaxf(acc, 0.f);
    }
    __syncthreads();
    for (int i = tid; i < DH * DH; i += 256) {
        int r = i / DH, c = i - r * DH;
        sh.prep.hw[r * 101 + c] = hW2[k * DH * DH + i];
    }
    __syncthreads();
    if (tid < DH) {
        float acc = hb2[k * DH + tid];
        for (int i = 0; i < DH; ++i) acc = fmaf(sh.prep.hw[tid * 101 + i], sh.prep.bufB[i], acc);
        sh.prep.bufA[tid] = fmaxf(acc, 0.f);
    }
    __syncthreads();
    if (tid < 2) {
        float acc = hb3[k * 2 + tid];
        const float* w = hW3 + (size_t)(k * 2 + tid) * DH;
        for (int i = 0; i < DH; ++i) acc = fmaf(w[i], sh.prep.bufA[i], acc);
        if (tid == 0) { ws[WS_OH0 + k] = acc; if (o0e1_s) o0e1_s[0] = acc; }
        else { float e = expf(acc); ws[WS_EOH1 + k] = e; if (o0e1_s) o0e1_s[1] = e; }
    }
    __syncthreads();
}

__device__ __forceinline__ float quadz(const float* __restrict__ tab_s,
                                       const float* __restrict__ xsc_s,
                                       const float* __restrict__ ccw_s,
                                       float x, float u0, float invd, int psub)
{
    float z = 0.f;
    for (int p = psub; p < 101; p += 4) {
        float u = x * xsc_s[p];
        float tt = fminf(fmaxf((u - u0) * invd, 0.f), (float)(G - 1) - 0.001f);
        int i = (int)tt;
        float f = tt - (float)i;
        float g0 = tab_s[i];
        float g1 = tab_s[i + 1];
        z = fmaf(ccw_s[p], fmaf(f, g1 - g0, g0), z);
    }
    z += __shfl_xor(z, 1, 64);
    z += __shfl_xor(z, 2, 64);
    return z;
}

// Single kernel, ONE grid barrier + one producer/consumer flag.
// Prologue (all blocks): full-array logits min/max (replicated -> no exchange)
//   + passthrough of own slice.
// Pre-barrier roles:
//   b 0-31 : build tables 0,1 (range known locally)
//   b 32-47: stage net-2 weights, poll probe flag, build table 2
//   b 48   : self-contained probe (ccw/xsc local, h-MLP net 0 -> publish,
//            endpoint MFMA, x2 range -> publish RNG2 + flag)
//   b 49,50: h-MLP nets 1,2 -> publish
//   b 51   : ccw/xsc consts -> publish (for eval)
// gridbar -> eval: stage 3 tables, y1 + register-chained x2->y2.
__global__ __launch_bounds__(256, 2)
void mega_kernel(const float* __restrict__ logits,
                 const float* __restrict__ iW0, const float* __restrict__ ib0,
                 const float* __restrict__ iW1, const float* __restrict__ ib1,
                 const float* __restrict__ iW2, const float* __restrict__ ib2,
                 const float* __restrict__ iW3, const float* __restrict__ ib3,
                 const float* __restrict__ hb0,
                 const float* __restrict__ hW1, const float* __restrict__ hb1,
                 const float* __restrict__ hW2, const float* __restrict__ hb2,
                 const float* __restrict__ hW3, const float* __restrict__ hb3,
                 float* __restrict__ ws, float* __restrict__ out, int n)
{
    __shared__ MegaSh sh;
    __shared__ float xsc_s[104], ccw_s[104];
    __shared__ float rmin_s[4], rmax_s[4];
    __shared__ float xmM_s[2];
    __shared__ float o0e1_s[2];

    int* bar = (int*)(ws + WS_BAR);
    const int tid = threadIdx.x;
    const int b = blockIdx.x;
    const int lane = tid & 63;
    const int wv = tid >> 6;
    const int hf = lane >> 5;
    const bool hfb = (hf != 0);
    const int l31 = lane & 31;
    const int spb = (n + NBLK - 1) / NBLK;      // 256 at n=16384
    const int ibeg = b * spb;
    const int iend = (ibeg + spb < n) ? (ibeg + spb) : n;

    // ---- prologue: replicated full-array min/max + own-slice passthrough ----
    {
        float lmin = 1e30f, lmax = -1e30f;
        for (int i = tid; i < n; i += 256) {
            float v = logits[i];
            lmin = fminf(lmin, v);
            lmax = fmaxf(lmax, v);
        }
        for (int i = ibeg + tid; i < iend; i += 256)
            out[2 * n + i] = logits[i];
        #pragma unroll
        for (int off = 1; off < 64; off <<= 1) {
            lmin = fminf(lmin, __shfl_xor(lmin, off, 64));
            lmax = fmaxf(lmax, __shfl_xor(lmax, off, 64));
        }
        if (lane == 0) { rmin_s[wv] = lmin; rmax_s[wv] = lmax; }
    }
    __syncthreads();
    const float xm = fminf(fminf(rmin_s[0], rmin_s[1]), fminf(rmin_s[2], rmin_s[3]));
    const float xM = fmaxf(fmaxf(rmax_s[0], rmax_s[1]), fmaxf(rmax_s[2], rmax_s[3]));
    // table-0/1 range (identical on every block: same data, same FP order)
    const float um01 = fminf(xm, 0.f);
    const float uM01 = fmaxf(xM, 0.f);
    const float span01 = fmaxf(uM01 - um01, 1e-5f);
    const float dlt01 = span01 * (1.f / (float)(G - 1));
    const float inv01 = (float)(G - 1) / span01;

    unsigned int zoff = 0;
    asm volatile("" : "+v"(zoff));   // opaque zero (keeps LDS reads un-cached)

    int wrow[4];
    #pragma unroll
    for (int nt = 0; nt < 4; ++nt) {
        int r = nt * 32 + l31;
        wrow[nt] = ((r > DH - 1) ? (DH - 1) : r) * WSTR + hf * 8;
    }

    // ---------------- pre-barrier roles ----------------
    if (b < 48) {
        const int kk = b >> 4;
        stage_net(sh, kk, tid, iW0, ib0, iW1, ib1, iW2, ib2, iW3);
        __syncthreads();

        if (b < 32) {
            // tables 0,1: range known locally, no waiting
            const float b3 = ib3[kk];
            float* __restrict__ tab = ws + WS_TAB + kk * G;
            int mr[2];
            h2 uu[2];
            #pragma unroll
            for (int j = 0; j < 2; ++j) {
                mr[j] = (b & 15) * 256 + j * 128 + wv * 32 + l31;
                float u = fmaf((float)mr[j], dlt01, um01);
                uu[j] = hpk2(u, u);
            }
            float dz[2];
            mlp2(sh.mlp.W1, sh.mlp.W2, sh.mlp.w0p, sh.mlp.b0p, sh.mlp.w3p,
                 uu, wrow, hf, hfb, b3, zoff, dz);
            #pragma unroll
            for (int j = 0; j < 2; ++j) if (!hfb) tab[mr[j]] = dz[j];
        } else {
            // table 2: weights staged (overlapped); wait on probe flag
            if (tid == 0) {
                while (__hip_atomic_load(&bar[35], __ATOMIC_RELAXED,
                                         __HIP_MEMORY_SCOPE_AGENT) == 0)
                    __builtin_amdgcn_s_sleep(2);
                __threadfence();   // acquire WS_RNG[8..10]
            }
            __syncthreads();
            const float u0 = ws[WS_RNG + 8];
            const float dlt = ws[WS_RNG + 9];
            const float b3 = ib3[2];
            float* __restrict__ tab = ws + WS_TAB + 2 * G;
            int mr[2];
            h2 uu[2];
            #pragma unroll
            for (int j = 0; j < 2; ++j) {
                mr[j] = (b & 15) * 256 + j * 128 + wv * 32 + l31;
                float u = fmaf((float)mr[j], dlt, u0);
                uu[j] = hpk2(u, u);
            }
            float dz[2];
            mlp2(sh.mlp.W1, sh.mlp.W2, sh.mlp.w0p, sh.mlp.b0p, sh.mlp.w3p,
                 uu, wrow, hf, hfb, b3, zoff, dz);
            #pragma unroll
            for (int j = 0; j < 2; ++j) if (!hfb) tab[mr[j]] = dz[j];
        }
    } else if (b == 48) {
        // ---- self-contained probe ----
        // local CC consts (float path: exact mod-200 reduction, small-arg cosf)
        if (tid <= 100) {
            const int t = tid;
            float ccw = 0.f;
            for (int j = 0; j <= 100; j += 2) {
                float wj = (j == 0) ? 1.f : 2.f / (1.f - (float)(j * j));
                float lam;
                if (t == 0) lam = 0.5f;
                else {
                    int r = (j * t) % 200;
                    lam = cosf((float)r * 0.031415926535f);   // r*pi/100
                    if (t == 100) lam *= 0.5f;
                }
                ccw = fmaf(lam * wj, 0.02f, ccw);
            }
            ccw_s[tid] = ccw;
            xsc_s[tid] = (cosf((float)tid * 0.031415926535f) + 1.f) * 0.5f;
        }
        // h-MLP net 0 -> publish + LDS copy
        hmlp(sh, 0, tid, hb0, hW1, hb1, hW2, hb2, hW3, hb3, ws, o0e1_s);
        // stage net-0 MLP weights (sh.mlp reuses sh.prep space; synced inside)
        stage_net(sh, 0, tid, iW0, ib0, iW1, ib1, iW2, ib2, iW3);
        __syncthreads();
        // endpoint rows: r = e*101 + p (e: xmin/xmax, p: quadrature point)
        const float b3 = ib3[0];
        int rr[2];
        h2 uu[2];
        #pragma unroll
        for (int j = 0; j < 2; ++j) {
            rr[j] = j * 128 + wv * 32 + l31;
            int r = rr[j];
            float xe = (r < 101) ? xm : xM;
            int p = (r < 101) ? r : (r - 101);
            if (p > 100) p = 0;
            float u = (r < 202) ? xe * xsc_s[p] : 0.f;
            uu[j] = hpk2(u, u);
        }
        float dz[2];
        mlp2(sh.mlp.W1, sh.mlp.W2, sh.mlp.w0p, sh.mlp.b0p, sh.mlp.w3p,
             uu, wrow, hf, hfb, b3, zoff, dz);
        #pragma unroll
        for (int j = 0; j < 2; ++j) if (!hfb) sh.mlp.g[rr[j]] = dz[j];
        __syncthreads();

        // quadrature at both endpoints -> x2 range -> net-2 table consts
        if (tid < 64) {
            float s0a = 0.f, s1a = 0.f;
            for (int p = tid; p < 101; p += 64) {
                float c = ccw_s[p];
                s0a = fmaf(c, sh.mlp.g[p], s0a);
                s1a = fmaf(c, sh.mlp.g[101 + p], s1a);
            }
            #pragma unroll
            for (int off = 1; off < 64; off <<= 1) {
                s0a += __shfl_xor(s0a, off, 64);
                s1a += __shfl_xor(s1a, off, 64);
            }
            if (tid == 0) {
                float z0 = 0.5f * xm * s0a;
                float z1 = 0.5f * xM * s1a;
                float o0 = o0e1_s[0], e1 = o0e1_s[1];
                float a = fmaf(e1, z0, o0);
                float bb = fmaf(e1, z1, o0);
                float x2m = fminf(a, bb), x2M = fmaxf(a, bb);
                float sp = fmaxf(x2M - x2m, 1e-6f);
                x2m -= 0.02f * sp;                 // safety margin: quadrature
                x2M += 0.02f * sp;                 // wiggle + table-lerp error
                float um = fminf(x2m, 0.f), uM = fmaxf(x2M, 0.f);
                float span = fmaxf(uM - um, 1e-5f);
                ws[WS_RNG + 8]  = um;
                ws[WS_RNG + 9]  = span * (1.f / (float)(G - 1));
                ws[WS_RNG + 10] = (float)(G - 1) / span;
                __threadfence();   // release WS_RNG[8..10]
                __hip_atomic_store(&bar[35], 1, __ATOMIC_RELAXED,
                                   __HIP_MEMORY_SCOPE_AGENT);
            }
        }
    } else if (b == 49 || b == 50) {
        hmlp(sh, b - 48, tid, hb0, hW1, hb1, hW2, hb2, hW3, hb3, ws, (float*)0);
    } else if (b == 51) {
        // CC consts for eval phase
        if (tid <= 100) {
            const int t = tid;
            float ccw = 0.f;
            for (int j = 0; j <= 100; j += 2) {
                float wj = (j == 0) ? 1.f : 2.f / (1.f - (float)(j * j));
                float lam;
                if (t == 0) lam = 0.5f;
                else {
                    int r = (j * t) % 200;
                    lam = cosf((float)r * 0.031415926535f);
                    if (t == 100) lam *= 0.5f;
                }
                ccw = fmaf(lam * wj, 0.02f, ccw);
            }
            ws[WS_CCW + tid] = ccw;
            ws[WS_XSC + tid] = (cosf((float)t * 0.031415926535f) + 1.f) * 0.5f;
        }
    }
    gridbar(bar, 0);

    // ---------------- eval ----------------
    {
        const float* tg = ws + WS_TAB;
        for (int i = tid * 4; i < 3 * G; i += 1024)
            *(float4*)&sh.ev.tab[i] = *(const float4*)&tg[i];
        if (tid < 101) {
            xsc_s[tid] = ws[WS_XSC + tid];
            ccw_s[tid] = ws[WS_CCW + tid];
        }
        __syncthreads();

        const float u02 = ws[WS_RNG + 8], iv2v = ws[WS_RNG + 10];
        const float o00 = ws[WS_OH0 + 0], e10 = ws[WS_EOH1 + 0];
        const float o01 = ws[WS_OH0 + 1], e11 = ws[WS_EOH1 + 1];
        const float o02 = ws[WS_OH0 + 2], e12 = ws[WS_EOH1 + 2];
        const int psub = tid & 3;

        for (int nn0 = ibeg; nn0 < iend; nn0 += 64) {
            int nn = nn0 + (tid >> 2);
            bool valid = (nn < iend);
            float x = valid ? logits[nn] : 0.f;

            float z1 = quadz(sh.ev.tab + G, xsc_s, ccw_s, x, um01, inv01, psub);
            float y1v = fmaf(e11, 0.5f * x * z1, o01);

            float z0 = quadz(sh.ev.tab, xsc_s, ccw_s, x, um01, inv01, psub);
            float x2 = fmaf(e10, 0.5f * x * z0, o00);

            float z2 = quadz(sh.ev.tab + 2 * G, xsc_s, ccw_s, x2, u02, iv2v, psub);
            float y2v = fmaf(e12, 0.5f * x2 * z2, o02);

            if (valid && psub == 0) {
                out[nn] = y1v;
                out[n + nn] = y2v;
            }
        }
    }
}

extern "C" void kernel_launch(void* const* d_in, const int* in_sizes, int n_in,
                              void* d_out, int out_size, void* d_ws, size_t ws_size,
                              hipStream_t stream)
{
    const float* logits = (const float*)d_in[0];
    const float* iW0 = (const float*)d_in[2];
    const float* ib0 = (const float*)d_in[3];
    const float* iW1 = (const float*)d_in[4];
    const float* ib1 = (const float*)d_in[5];
    const float* iW2 = (const float*)d_in[6];
    const float* ib2 = (const float*)d_in[7];
    const float* iW3 = (const float*)d_in[8];
    const float* ib3 = (const float*)d_in[9];
    const float* hb0 = (const float*)d_in[11];
    const float* hW1 = (const float*)d_in[12];
    const float* hb1 = (const float*)d_in[13];
    const float* hW2 = (const float*)d_in[14];
    const float* hb2 = (const float*)d_in[15];
    const float* hW3 = (const float*)d_in[16];
    const float* hb3 = (const float*)d_in[17];
    float* out = (float*)d_out;
    float* ws = (float*)d_ws;
    int n = in_sizes[0];

    // zero the barrier counters + flags (captured per-iteration)
    hipMemsetAsync((void*)(ws + WS_BAR), 0, 40 * sizeof(int), stream);

    hipLaunchKernelGGL(mega_kernel, dim3(NBLK), dim3(256), 0, stream,
                       logits, iW0, ib0, iW1, ib1, iW2, ib2, iW3, ib3,
                       hb0, hW1, hb1, hW2, hb2, hW3, hb3, ws, out, n);
}

// Round 9
// 142.844 us; speedup vs baseline: 1.1874x; 1.1874x over previous
//
#include <hip/hip_runtime.h>
#include <hip/hip_bf16.h>
#include <hip/hip_fp16.h>
#include <math.h>

typedef _Float16 f16x8 __attribute__((ext_vector_type(8)));
typedef _Float16 f16x4 __attribute__((ext_vector_type(4)));
typedef _Float16 h2 __attribute__((ext_vector_type(2)));
typedef __fp16 h2amd __attribute__((ext_vector_type(2)));   // builtin return type
typedef float f32x16 __attribute__((ext_vector_type(16)));
typedef float f32x2 __attribute__((ext_vector_type(2)));

#define DH 100      // hidden dim
#define G  4096     // table size per net
#define WSTR 120    // LDS row stride in f16 elems
#define NBLK 128    // <= 256 CUs => co-resident by capacity
#define NBARX (NBLK - 17)   // partial barrier: blocks 32..48 excluded
#define SPIN_MAX 2000000    // watchdog: ~0.1s worst case, then fall through
                            // (audited graph never triggers it; if triggered,
                            // kernel completes with wrong values -> diagnosable)

// ws float offsets
#define WS_CCW   0      // [0,101)
#define WS_XSC   128    // [128,229)
#define WS_OH0   256    // 3
#define WS_EOH1  260    // 3
#define WS_RNG   800    // net-2 {u0, dlt, inv} at [808,811)
#define WS_BAR   960    // int region (160 ints)
#define WS_TAB   17408  // 3*G table floats

// bar int indices (each flag on its own 128B cacheline)
#define CNT_X    0      // partial-barrier arrivals
#define CNT_T2   16     // build-2 completions
#define FLG_X    32     // partial barrier released
#define FLG_T2   64     // table 2 ready
#define FLG_OE   96     // net-0 h-MLP (o0,e1) published
#define FLG_RNG  128    // net-2 range published

__device__ __forceinline__ unsigned short f2bf(float f) {
    unsigned int u = __float_as_uint(f);
    unsigned int r = (u + 0x7FFFu + ((u >> 16) & 1u)) >> 16;  // RNE
    return (unsigned short)r;
}
__device__ __forceinline__ unsigned int hpk(float a, float b) {
    union { h2amd h; unsigned int u; } c;
    c.h = __builtin_amdgcn_cvt_pkrtz(a, b);
    return c.u;
}
__device__ __forceinline__ h2 hpk2(float a, float b) {
    union { h2amd ha; h2 h; } c;
    c.ha = __builtin_amdgcn_cvt_pkrtz(a, b);
    return c.h;
}

// arrival: relaxed add; last arriver sets a flag on a separate line.
__device__ __forceinline__ void bar_arrive(int* bar, int cnt, int flg, int target) {
    __syncthreads();
    if (threadIdx.x == 0) {
        __threadfence();   // release this block's global writes
        int old = __hip_atomic_fetch_add(&bar[cnt], 1, __ATOMIC_RELAXED,
                                         __HIP_MEMORY_SCOPE_AGENT);
        if (old == target - 1)
            __hip_atomic_store(&bar[flg], 1, __ATOMIC_RELAXED,
                               __HIP_MEMORY_SCOPE_AGENT);
    }
}
// wait: poll write-once flag with relaxed loads (BOUNDED); acquire on exit.
__device__ __forceinline__ void bar_wait(int* bar, int flg) {
    if (threadIdx.x == 0) {
        int spins = 0;
        while (__hip_atomic_load(&bar[flg], __ATOMIC_RELAXED,
                                 __HIP_MEMORY_SCOPE_AGENT) == 0) {
            __builtin_amdgcn_s_sleep(2);
            if (++spins > SPIN_MAX) break;   // watchdog: never wedge the GPU
        }
        __threadfence();   // acquire
    }
    __syncthreads();
}

union FR { f16x8 v; h2 h[4]; unsigned int u32[4]; };

// phase-overlaid LDS (max member ~49.8 KB)
union MegaSh {
    struct { float hw[DH * 101]; float bufA[128]; float bufB[128]; } prep;
    struct {
        __align__(16) _Float16 W1[DH * WSTR];
        __align__(16) _Float16 W2[DH * WSTR];
        unsigned int w0p[64], b0p[64], w3p[64];
        float g[256];
    } mlp;
    struct { __align__(16) float tab[3 * G]; } ev;
};

// verified transposed MFMA dataflow (lane^32 exchange, laundered LDS reads):
// evaluates g(u)=elu(MLP(u))+1 for two 128-row groups; dzout valid on !hfb.
__device__ __forceinline__ void mlp2(const _Float16* __restrict__ W1s,
                                     const _Float16* __restrict__ W2s,
                                     const unsigned int* __restrict__ w0p_s,
                                     const unsigned int* __restrict__ b0p_s,
                                     const unsigned int* __restrict__ w3p_s,
                                     const h2* uu, const int* wrow,
                                     const int hf, const bool hfb,
                                     const float b3, unsigned int zoff,
                                     float* dzout)
{
    const f32x2 zero2 = {0.f, 0.f};

    FR a1[2][7];
    #pragma unroll
    for (int ks = 0; ks < 7; ++ks) {
        int pb = ks * 8 + hf * 4 + zoff;
        uint4 wq = *(const uint4*)&w0p_s[pb];
        uint4 bq = *(const uint4*)&b0p_s[pb];
        unsigned int wqa[4] = {wq.x, wq.y, wq.z, wq.w};
        unsigned int bqa[4] = {bq.x, bq.y, bq.z, bq.w};
        #pragma unroll
        for (int i = 0; i < 4; ++i) {
            union { unsigned int u; h2 h; } cw, cb;
            cw.u = wqa[i]; cb.u = bqa[i];
            h2 z = {(_Float16)0.f, (_Float16)0.f};
            #pragma unroll
            for (int j = 0; j < 2; ++j) {
                h2 r = __builtin_elementwise_fma(uu[j], cw.h, cb.h);
                a1[j][ks].h[i] = __builtin_elementwise_max(r, z);
            }
        }
    }

    FR f3[2][7];
    #pragma unroll
    for (int nt = 0; nt < 4; ++nt) {
        f32x16 acc[2];
        #pragma unroll
        for (int r = 0; r < 16; ++r) { acc[0][r] = 0.f; acc[1][r] = 0.f; }
        #pragma unroll
        for (int ks = 0; ks < 7; ++ks) {
            f16x8 wA = *(const f16x8*)&W1s[wrow[nt] + ks * 16 + zoff];
            acc[0] = __builtin_amdgcn_mfma_f32_32x32x16_f16(wA, a1[0][ks].v, acc[0], 0, 0, 0);
            acc[1] = __builtin_amdgcn_mfma_f32_32x32x16_f16(wA, a1[1][ks].v, acc[1], 0, 0, 0);
        }
        #pragma unroll
        for (int j = 0; j < 2; ++j) {
            if (nt < 3) {
                unsigned int pk[4][2];
                #pragma unroll
                for (int qi = 0; qi < 4; ++qi) {
                    f32x2 lo = {acc[j][4 * qi + 0], acc[j][4 * qi + 1]};
                    f32x2 hi = {acc[j][4 * qi + 2], acc[j][4 * qi + 3]};
                    lo = __builtin_elementwise_max(lo, zero2);
                    hi = __builtin_elementwise_max(hi, zero2);
                    pk[qi][0] = hpk(lo[0], lo[1]);
                    pk[qi][1] = hpk(hi[0], hi[1]);
                }
                #pragma unroll
                for (int kk = 0; kk < 2; ++kk) {
                    unsigned int X0 = hfb ? pk[2 * kk][0] : pk[2 * kk + 1][0];
                    unsigned int X1 = hfb ? pk[2 * kk][1] : pk[2 * kk + 1][1];
                    unsigned int O0 = hfb ? pk[2 * kk + 1][0] : pk[2 * kk][0];
                    unsigned int O1 = hfb ? pk[2 * kk + 1][1] : pk[2 * kk][1];
                    unsigned int Y0 = (unsigned int)__shfl_xor((int)X0, 32, 64);
                    unsigned int Y1 = (unsigned int)__shfl_xor((int)X1, 32, 64);
                    f3[j][nt * 2 + kk].u32[0] = hfb ? Y0 : O0;
                    f3[j][nt * 2 + kk].u32[1] = hfb ? Y1 : O1;
                    f3[j][nt * 2 + kk].u32[2] = hfb ? O0 : Y0;
                    f3[j][nt * 2 + kk].u32[3] = hfb ? O1 : Y1;
                }
            } else {
                f32x2 lo = {acc[j][0], acc[j][1]};
                f32x2 hi = {acc[j][2], acc[j][3]};
                lo = __builtin_elementwise_max(lo, zero2);
                hi = __builtin_elementwise_max(hi, zero2);
                unsigned int p0 = hpk(lo[0], lo[1]);
                unsigned int p1 = hpk(hi[0], hi[1]);
                f3[j][6].u32[0] = hfb ? 0u : p0;
                f3[j][6].u32[1] = hfb ? 0u : p1;
                f3[j][6].u32[2] = hfb ? 0u : 0x00003C00u;   // f16 1.0 (bias slot)
                f3[j][6].u32[3] = 0u;
            }
        }
    }

    f32x2 oacc2[2] = {{0.f, 0.f}, {0.f, 0.f}};
    #pragma unroll
    for (int nt2 = 0; nt2 < 4; ++nt2) {
        f32x16 acc2[2];
        #pragma unroll
        for (int r = 0; r < 16; ++r) { acc2[0][r] = 0.f; acc2[1][r] = 0.f; }
        #pragma unroll
        for (int ks = 0; ks < 7; ++ks) {
            f16x8 wA = *(const f16x8*)&W2s[wrow[nt2] + ks * 16 + zoff];
            acc2[0] = __builtin_amdgcn_mfma_f32_32x32x16_f16(wA, f3[0][ks].v, acc2[0], 0, 0, 0);
            acc2[1] = __builtin_amdgcn_mfma_f32_32x32x16_f16(wA, f3[1][ks].v, acc2[1], 0, 0, 0);
        }
        uint4 wa = *(const uint4*)&w3p_s[hf * 32 + nt2 * 8 + zoff];
        uint4 wb2 = *(const uint4*)&w3p_s[hf * 32 + nt2 * 8 + 4 + zoff];
        unsigned int w8[8] = {wa.x, wa.y, wa.z, wa.w, wb2.x, wb2.y, wb2.z, wb2.w};
        f32x2 w3v[8];
        #pragma unroll
        for (int q = 0; q < 8; ++q) {
            w3v[q][0] = __uint_as_float(w8[q] << 16);
            w3v[q][1] = __uint_as_float(w8[q] & 0xFFFF0000u);
        }
        #pragma unroll
        for (int j = 0; j < 2; ++j)
            #pragma unroll
            for (int qi = 0; qi < 4; ++qi) {
                f32x2 lo = {acc2[j][4 * qi + 0], acc2[j][4 * qi + 1]};
                f32x2 hi = {acc2[j][4 * qi + 2], acc2[j][4 * qi + 3]};
                lo = __builtin_elementwise_max(lo, zero2);
                hi = __builtin_elementwise_max(hi, zero2);
                oacc2[j] = __builtin_elementwise_fma(lo, w3v[qi * 2], oacc2[j]);
                oacc2[j] = __builtin_elementwise_fma(hi, w3v[qi * 2 + 1], oacc2[j]);
            }
    }

    #pragma unroll
    for (int j = 0; j < 2; ++j) {
        float oacc = oacc2[j][0] + oacc2[j][1];
        float o = oacc + __shfl_xor(oacc, 32, 64) + b3;
        dzout[j] = (o > 0.f) ? (o + 1.f) : expf(o);   // elu(o) + 1
    }
}

// vectorized weight staging (float4 loads, RNE f16 convert, ds_write_b64)
__device__ __forceinline__ void stage_net(MegaSh& sh, int kk, int tid,
                                          const float* __restrict__ iW0,
                                          const float* __restrict__ ib0,
                                          const float* __restrict__ iW1,
                                          const float* __restrict__ ib1,
                                          const float* __restrict__ iW2,
                                          const float* __restrict__ ib2,
                                          const float* __restrict__ iW3)
{
    if (tid < 64) {
        int s0 = 2 * tid, s1 = 2 * tid + 1;
        float w0a = (s0 < DH) ? iW0[(kk * DH + s0) * 3] : 0.f;   // h==0: feature 0 only
        float w0b = (s1 < DH) ? iW0[(kk * DH + s1) * 3] : 0.f;
        float b0a = (s0 < DH) ? ib0[kk * DH + s0] : ((s0 == DH) ? 1.f : 0.f);
        float b0b = (s1 < DH) ? ib0[kk * DH + s1] : 0.f;
        sh.mlp.w0p[tid] = hpk(w0a, w0b);
        sh.mlp.b0p[tid] = hpk(b0a, b0b);

        int hf_i = tid >> 5, rem = tid & 31;
        int nt2 = rem >> 3, qq = (rem >> 1) & 3, pr = rem & 1;
        int n2e = 32 * nt2 + 8 * qq + 2 * pr + 4 * hf_i;
        float we = (n2e < DH) ? iW3[kk * DH + n2e] : 0.f;
        float wo = (n2e + 1 < DH) ? iW3[kk * DH + n2e + 1] : 0.f;
        sh.mlp.w3p[tid] = ((unsigned int)f2bf(wo) << 16) | (unsigned int)f2bf(we);
    }
    // main body: DH*DH = 2500 float4 per matrix (rows are 25 float4 each)
    const float4* W1g4 = (const float4*)(iW1 + (size_t)kk * DH * DH);
    const float4* W2g4 = (const float4*)(iW2 + (size_t)kk * DH * DH);
    for (int i4 = tid; i4 < (DH * DH) / 4; i4 += 256) {
        int r = i4 / 25, c4 = (i4 - r * 25) * 4;
        float4 a = W1g4[i4], bq = W2g4[i4];
        f16x4 va = {(_Float16)a.x, (_Float16)a.y, (_Float16)a.z, (_Float16)a.w};
        f16x4 vb = {(_Float16)bq.x, (_Float16)bq.y, (_Float16)bq.z, (_Float16)bq.w};
        *(f16x4*)&sh.mlp.W1[r * WSTR + c4] = va;
        *(f16x4*)&sh.mlp.W2[r * WSTR + c4] = vb;
    }
    // bias column (c==DH) + zero pad cols 101..119
    for (int i = tid; i < DH * 20; i += 256) {
        int r = i / 20, c = DH + (i - (i / 20) * 20);
        _Float16 v1 = (c == DH) ? (_Float16)ib1[kk * DH + r] : (_Float16)0.f;
        _Float16 v2 = (c == DH) ? (_Float16)ib2[kk * DH + r] : (_Float16)0.f;
        sh.mlp.W1[r * WSTR + c] = v1;
        sh.mlp.W2[r * WSTR + c] = v2;
    }
}

// h-MLP for one net using sh.prep; publishes o0/e1 to ws.
__device__ __forceinline__ void hmlp(MegaSh& sh, int k, int tid,
                                     const float* __restrict__ hb0,
                                     const float* __restrict__ hW1,
                                     const float* __restrict__ hb1,
                                     const float* __restrict__ hW2,
                                     const float* __restrict__ hb2,
                                     const float* __restrict__ hW3,
                                     const float* __restrict__ hb3,
                                     float* __restrict__ ws)
{
    if (tid < 128) sh.prep.bufA[tid] = (tid < DH) ? fmaxf(hb0[k * DH + tid], 0.f) : 0.f;
    __syncthreads();
    for (int i = tid; i < DH * DH; i += 256) {
        int r = i / DH, c = i - r * DH;
        sh.prep.hw[r * 101 + c] = hW1[k * DH * DH + i];
    }
    __syncthreads();
    if (tid < DH) {
        float acc = hb1[k * DH + tid];
        for (int i = 0; i < DH; ++i) acc = fmaf(sh.prep.hw[tid * 101 + i], sh.prep.bufA[i], acc);
        sh.prep.bufB[tid] = fmaxf(acc, 0.f);
    }
    __syncthreads();
    for (int i = tid; i < DH * DH; i += 256) {
        int r = i / DH, c = i - r * DH;
        sh.prep.hw[r * 101 + c] = hW2[k * DH * DH + i];
    }
    __syncthreads();
    if (tid < DH) {
        float acc = hb2[k * DH + tid];
        for (int i = 0; i < DH; ++i) acc = fmaf(sh.prep.hw[tid * 101 + i], sh.prep.bufB[i], acc);
        sh.prep.bufA[tid] = fmaxf(acc, 0.f);
    }
    __syncthreads();
    if (tid < 2) {
        float acc = hb3[k * 2 + tid];
        const float* w = hW3 + (size_t)(k * 2 + tid) * DH;
        for (int i = 0; i < DH; ++i) acc = fmaf(w[i], sh.prep.bufA[i], acc);
        if (tid == 0) ws[WS_OH0 + k] = acc;
        else          ws[WS_EOH1 + k] = expf(acc);
    }
    __syncthreads();
}

__device__ __forceinline__ void cc_consts(float* __restrict__ dst_ccw,
                                          float* __restrict__ dst_xsc, int tid)
{
    // cos(j*t*pi/100) has period 200 in (j*t): exact integer reduction,
    // then small-arg cosf (f32 error ~1e-6 on O(0.02) weights).
    if (tid <= 100) {
        const int t = tid;
        float ccw = 0.f;
        for (int j = 0; j <= 100; j += 2) {
            float wj = (j == 0) ? 1.f : 2.f / (1.f - (float)(j * j));
            float lam;
            if (t == 0) lam = 0.5f;
            else {
                int r = (j * t) % 200;
                lam = cosf((float)r * 0.031415926535f);   // r*pi/100
                if (t == 100) lam *= 0.5f;
            }
            ccw = fmaf(lam * wj, 0.02f, ccw);
        }
        dst_ccw[tid] = ccw;
        dst_xsc[tid] = (cosf((float)t * 0.031415926535f) + 1.f) * 0.5f;
    }
}

__device__ __forceinline__ float quadz(const float* __restrict__ tab_s,
                                       const float* __restrict__ xsc_s,
                                       const float* __restrict__ ccw_s,
                                       float x, float u0, float invd, int psub)
{
    float z = 0.f;
    for (int p = psub; p < 101; p += 4) {
        float u = x * xsc_s[p];
        float tt = fminf(fmaxf((u - u0) * invd, 0.f), (float)(G - 1) - 0.001f);
        int i = (int)tt;
        float f = tt - (float)i;
        float g0 = tab_s[i];
        float g1 = tab_s[i + 1];
        z = fmaf(ccw_s[p], fmaf(f, g1 - g0, g0), z);
    }
    z += __shfl_xor(z, 1, 64);
    z += __shfl_xor(z, 2, 64);
    return z;
}

// Single kernel; partial barrier + flag chain takes probe/build-2 off the tail:
//  all   : prologue (replicated min/max + passthrough)
//  b 0-31: build tables 0,1 -> arrive barX
//  b32-47: stage net-2, wait RNG flag, build table 2, count -> FLG_T2 (no barX)
//  b 48  : probe: cc + stage net-0 + endpoint MFMA, wait FLG_OE, range -> FLG_RNG
//  b 49  : h-MLP net 0 -> FLG_OE -> arrive;  b50/51: h-MLP 1,2 -> arrive
//  b 52  : cc consts -> ws -> arrive;  b53+: arrive
//  all   : wait FLG_X -> stage tabs 0,1 -> y1 + x2 (regs)
//          -> wait FLG_T2 -> stage tab 2 -> y2
// Dependency graph is acyclic; all waits bounded by SPIN_MAX watchdog.
__global__ __launch_bounds__(256, 2)
void mega_kernel(const float* __restrict__ logits,
                 const float* __restrict__ iW0, const float* __restrict__ ib0,
                 const float* __restrict__ iW1, const float* __restrict__ ib1,
                 const float* __restrict__ iW2, const float* __restrict__ ib2,
                 const float* __restrict__ iW3, const float* __restrict__ ib3,
                 const float* __restrict__ hb0,
                 const float* __restrict__ hW1, const float* __restrict__ hb1,
                 const float* __restrict__ hW2, const float* __restrict__ hb2,
                 const float* __restrict__ hW3, const float* __restrict__ hb3,
                 float* __restrict__ ws, float* __restrict__ out, int n)
{
    __shared__ MegaSh sh;
    __shared__ float xsc_s[104], ccw_s[104];
    __shared__ float rmin_s[4], rmax_s[4];

    int* bar = (int*)(ws + WS_BAR);
    const int tid = threadIdx.x;
    const int b = blockIdx.x;
    const int lane = tid & 63;
    const int wv = tid >> 6;
    const int hf = lane >> 5;
    const bool hfb = (hf != 0);
    const int l31 = lane & 31;
    const int spb = (n + NBLK - 1) / NBLK;      // 128 at n=16384
    const int ibeg = b * spb;
    const int iend = (ibeg + spb < n) ? (ibeg + spb) : n;

    // ---- prologue: replicated full-array min/max + own-slice passthrough ----
    {
        float lmin = 1e30f, lmax = -1e30f;
        for (int i = tid; i < n; i += 256) {
            float v = logits[i];
            lmin = fminf(lmin, v);
            lmax = fmaxf(lmax, v);
        }
        for (int i = ibeg + tid; i < iend; i += 256)
            out[2 * n + i] = logits[i];
        #pragma unroll
        for (int off = 1; off < 64; off <<= 1) {
            lmin = fminf(lmin, __shfl_xor(lmin, off, 64));
            lmax = fmaxf(lmax, __shfl_xor(lmax, off, 64));
        }
        if (lane == 0) { rmin_s[wv] = lmin; rmax_s[wv] = lmax; }
    }
    __syncthreads();
    const float xm = fminf(fminf(rmin_s[0], rmin_s[1]), fminf(rmin_s[2], rmin_s[3]));
    const float xM = fmaxf(fmaxf(rmax_s[0], rmax_s[1]), fmaxf(rmax_s[2], rmax_s[3]));
    // table-0/1 range (identical on every block: same data, same FP order)
    const float um01 = fminf(xm, 0.f);
    const float uM01 = fmaxf(xM, 0.f);
    const float span01 = fmaxf(uM01 - um01, 1e-5f);
    const float dlt01 = span01 * (1.f / (float)(G - 1));
    const float inv01 = (float)(G - 1) / span01;

    unsigned int zoff = 0;
    asm volatile("" : "+v"(zoff));   // opaque zero (keeps LDS reads un-cached)

    int wrow[4];
    #pragma unroll
    for (int nt = 0; nt < 4; ++nt) {
        int r = nt * 32 + l31;
        wrow[nt] = ((r > DH - 1) ? (DH - 1) : r) * WSTR + hf * 8;
    }

    // ---------------- pre-barrier roles ----------------
    if (b < 32) {
        const int kk = b >> 4;
        stage_net(sh, kk, tid, iW0, ib0, iW1, ib1, iW2, ib2, iW3);
        __syncthreads();
        const float b3 = ib3[kk];
        float* __restrict__ tab = ws + WS_TAB + kk * G;
        int mr[2];
        h2 uu[2];
        #pragma unroll
        for (int j = 0; j < 2; ++j) {
            mr[j] = (b & 15) * 256 + j * 128 + wv * 32 + l31;
            float u = fmaf((float)mr[j], dlt01, um01);
            uu[j] = hpk2(u, u);
        }
        float dz[2];
        mlp2(sh.mlp.W1, sh.mlp.W2, sh.mlp.w0p, sh.mlp.b0p, sh.mlp.w3p,
             uu, wrow, hf, hfb, b3, zoff, dz);
        #pragma unroll
        for (int j = 0; j < 2; ++j) if (!hfb) tab[mr[j]] = dz[j];
        bar_arrive(bar, CNT_X, FLG_X, NBARX);
    } else if (b < 48) {
        // build table 2: stage overlapped, wait on probe's range flag
        stage_net(sh, 2, tid, iW0, ib0, iW1, ib1, iW2, ib2, iW3);
        __syncthreads();
        bar_wait(bar, FLG_RNG);
        const float u0 = ws[WS_RNG + 8];
        const float dlt = ws[WS_RNG + 9];
        const float b3 = ib3[2];
        float* __restrict__ tab = ws + WS_TAB + 2 * G;
        int mr[2];
        h2 uu[2];
        #pragma unroll
        for (int j = 0; j < 2; ++j) {
            mr[j] = (b & 15) * 256 + j * 128 + wv * 32 + l31;
            float u = fmaf((float)mr[j], dlt, u0);
            uu[j] = hpk2(u, u);
        }
        float dz[2];
        mlp2(sh.mlp.W1, sh.mlp.W2, sh.mlp.w0p, sh.mlp.b0p, sh.mlp.w3p,
             uu, wrow, hf, hfb, b3, zoff, dz);
        #pragma unroll
        for (int j = 0; j < 2; ++j) if (!hfb) tab[mr[j]] = dz[j];
        // completion count -> FLG_T2 (no barX arrival for these blocks)
        __syncthreads();
        if (tid == 0) {
            __threadfence();
            int old = __hip_atomic_fetch_add(&bar[CNT_T2], 1, __ATOMIC_RELAXED,
                                             __HIP_MEMORY_SCOPE_AGENT);
            if (old == 15)
                __hip_atomic_store(&bar[FLG_T2], 1, __ATOMIC_RELAXED,
                                   __HIP_MEMORY_SCOPE_AGENT);
        }
    } else if (b == 48) {
        // probe: cc consts + net-0 weights + endpoint MFMA; h-MLP via FLG_OE
        cc_consts(ccw_s, xsc_s, tid);
        stage_net(sh, 0, tid, iW0, ib0, iW1, ib1, iW2, ib2, iW3);
        __syncthreads();
        const float b3 = ib3[0];
        int rr[2];
        h2 uu[2];
        #pragma unroll
        for (int j = 0; j < 2; ++j) {
            rr[j] = j * 128 + wv * 32 + l31;
            int r = rr[j];
            float xe = (r < 101) ? xm : xM;
            int p = (r < 101) ? r : (r - 101);
            if (p > 100) p = 0;
            float u = (r < 202) ? xe * xsc_s[p] : 0.f;
            uu[j] = hpk2(u, u);
        }
        float dz[2];
        mlp2(sh.mlp.W1, sh.mlp.W2, sh.mlp.w0p, sh.mlp.b0p, sh.mlp.w3p,
             uu, wrow, hf, hfb, b3, zoff, dz);
        #pragma unroll
        for (int j = 0; j < 2; ++j) if (!hfb) sh.mlp.g[rr[j]] = dz[j];
        __syncthreads();
        bar_wait(bar, FLG_OE);   // net-0 (o0,e1) published by block 49

        if (tid < 64) {
            float s0a = 0.f, s1a = 0.f;
            for (int p = tid; p < 101; p += 64) {
                float c = ccw_s[p];
                s0a = fmaf(c, sh.mlp.g[p], s0a);
                s1a = fmaf(c, sh.mlp.g[101 + p], s1a);
            }
            #pragma unroll
            for (int off = 1; off < 64; off <<= 1) {
                s0a += __shfl_xor(s0a, off, 64);
                s1a += __shfl_xor(s1a, off, 64);
            }
            if (tid == 0) {
                float z0 = 0.5f * xm * s0a;
                float z1 = 0.5f * xM * s1a;
                float o0 = ws[WS_OH0 + 0], e1 = ws[WS_EOH1 + 0];
                float a = fmaf(e1, z0, o0);
                float bb = fmaf(e1, z1, o0);
                float x2m = fminf(a, bb), x2M = fmaxf(a, bb);
                float sp = fmaxf(x2M - x2m, 1e-6f);
                x2m -= 0.02f * sp;                 // safety margin: quadrature
                x2M += 0.02f * sp;                 // wiggle + table-lerp error
                float um = fminf(x2m, 0.f), uM = fmaxf(x2M, 0.f);
                float span = fmaxf(uM - um, 1e-5f);
                ws[WS_RNG + 8]  = um;
                ws[WS_RNG + 9]  = span * (1.f / (float)(G - 1));
                ws[WS_RNG + 10] = (float)(G - 1) / span;
                __threadfence();   // release WS_RNG[8..10]
                __hip_atomic_store(&bar[FLG_RNG], 1, __ATOMIC_RELAXED,
                                   __HIP_MEMORY_SCOPE_AGENT);
            }
        }
    } else if (b == 49) {
        hmlp(sh, 0, tid, hb0, hW1, hb1, hW2, hb2, hW3, hb3, ws);
        if (tid == 0) {
            __threadfence();
            __hip_atomic_store(&bar[FLG_OE], 1, __ATOMIC_RELAXED,
                               __HIP_MEMORY_SCOPE_AGENT);
        }
        bar_arrive(bar, CNT_X, FLG_X, NBARX);
    } else if (b == 50 || b == 51) {
        hmlp(sh, b - 49, tid, hb0, hW1, hb1, hW2, hb2, hW3, hb3, ws);
        bar_arrive(bar, CNT_X, FLG_X, NBARX);
    } else if (b == 52) {
        cc_consts(ws + WS_CCW, ws + WS_XSC, tid);
        bar_arrive(bar, CNT_X, FLG_X, NBARX);
    } else {
        bar_arrive(bar, CNT_X, FLG_X, NBARX);
    }

    // ---------------- eval part 1: y1 + x2 (tables 0,1 only) ----------------
    bar_wait(bar, FLG_X);
    {
        const float* tg = ws + WS_TAB;
        for (int i = tid * 4; i < 2 * G; i += 1024)
            *(float4*)&sh.ev.tab[i] = *(const float4*)&tg[i];
        if (tid < 101) {
            xsc_s[tid] = ws[WS_XSC + tid];
            ccw_s[tid] = ws[WS_CCW + tid];
        }
    }
    __syncthreads();

    const float o00 = ws[WS_OH0 + 0], e10 = ws[WS_EOH1 + 0];
    const float o01 = ws[WS_OH0 + 1], e11 = ws[WS_EOH1 + 1];
    const int psub = tid & 3;
    const bool hasA = (ibeg < iend);
    const bool hasB = (ibeg + 64 < iend);
    const int nnA = ibeg + (tid >> 2);
    const int nnB = ibeg + 64 + (tid >> 2);
    float xA = 0.f, xB = 0.f, x2A = 0.f, x2B = 0.f;

    if (hasA) {
        xA = (nnA < iend) ? logits[nnA] : 0.f;
        float z1 = quadz(sh.ev.tab + G, xsc_s, ccw_s, xA, um01, inv01, psub);
        float z0 = quadz(sh.ev.tab, xsc_s, ccw_s, xA, um01, inv01, psub);
        if (nnA < iend && psub == 0) out[nnA] = fmaf(e11, 0.5f * xA * z1, o01);
        x2A = fmaf(e10, 0.5f * xA * z0, o00);
    }
    if (hasB) {
        xB = (nnB < iend) ? logits[nnB] : 0.f;
        float z1 = quadz(sh.ev.tab + G, xsc_s, ccw_s, xB, um01, inv01, psub);
        float z0 = quadz(sh.ev.tab, xsc_s, ccw_s, xB, um01, inv01, psub);
        if (nnB < iend && psub == 0) out[nnB] = fmaf(e11, 0.5f * xB * z1, o01);
        x2B = fmaf(e10, 0.5f * xB * z0, o00);
    }

    // ---------------- eval part 2: y2 (table 2, usually already built) ------
    bar_wait(bar, FLG_T2);
    {
        const float* tg = ws + WS_TAB;
        for (int i = 2 * G + tid * 4; i < 3 * G; i += 1024)
            *(float4*)&sh.ev.tab[i] = *(const float4*)&tg[i];
    }
    __syncthreads();

    const float u02 = ws[WS_RNG + 8], iv2v = ws[WS_RNG + 10];
    const float o02 = ws[WS_OH0 + 2], e12 = ws[WS_EOH1 + 2];

    if (hasA) {
        float z2 = quadz(sh.ev.tab + 2 * G, xsc_s, ccw_s, x2A, u02, iv2v, psub);
        if (nnA < iend && psub == 0) out[n + nnA] = fmaf(e12, 0.5f * x2A * z2, o02);
    }
    if (hasB) {
        float z2 = quadz(sh.ev.tab + 2 * G, xsc_s, ccw_s, x2B, u02, iv2v, psub);
        if (nnB < iend && psub == 0) out[n + nnB] = fmaf(e12, 0.5f * x2B * z2, o02);
    }
}

extern "C" void kernel_launch(void* const* d_in, const int* in_sizes, int n_in,
                              void* d_out, int out_size, void* d_ws, size_t ws_size,
                              hipStream_t stream)
{
    const float* logits = (const float*)d_in[0];
    const float* iW0 = (const float*)d_in[2];
    const float* ib0 = (const float*)d_in[3];
    const float* iW1 = (const float*)d_in[4];
    const float* ib1 = (const float*)d_in[5];
    const float* iW2 = (const float*)d_in[6];
    const float* ib2 = (const float*)d_in[7];
    const float* iW3 = (const float*)d_in[8];
    const float* ib3 = (const float*)d_in[9];
    const float* hb0 = (const float*)d_in[11];
    const float* hW1 = (const float*)d_in[12];
    const float* hb1 = (const float*)d_in[13];
    const float* hW2 = (const float*)d_in[14];
    const float* hb2 = (const float*)d_in[15];
    const float* hW3 = (const float*)d_in[16];
    const float* hb3 = (const float*)d_in[17];
    float* out = (float*)d_out;
    float* ws = (float*)d_ws;
    int n = in_sizes[0];

    // zero counters + flags (captured per-iteration; replay-safe fall-through)
    hipMemsetAsync((void*)(ws + WS_BAR), 0, 160 * sizeof(int), stream);

    hipLaunchKernelGGL(mega_kernel, dim3(NBLK), dim3(256), 0, stream,
                       logits, iW0, ib0, iW1, ib1, iW2, ib2, iW3, ib3,
                       hb0, hW1, hb1, hW2, hb2, hW3, hb3, ws, out, n);
}

// Round 10
// 127.979 us; speedup vs baseline: 1.3253x; 1.1162x over previous
//
#include <hip/hip_runtime.h>
#include <hip/hip_bf16.h>
#include <hip/hip_fp16.h>
#include <math.h>

typedef _Float16 f16x8 __attribute__((ext_vector_type(8)));
typedef _Float16 f16x4 __attribute__((ext_vector_type(4)));
typedef _Float16 h2 __attribute__((ext_vector_type(2)));
typedef __fp16 h2amd __attribute__((ext_vector_type(2)));   // builtin return type
typedef float f32x16 __attribute__((ext_vector_type(16)));
typedef float f32x2 __attribute__((ext_vector_type(2)));

#define DH 100      // hidden dim
#define G  4096     // table size per net
#define WSTR 120    // LDS row stride in f16 elems
#define NBLK 128    // <= 256 CUs => co-resident by capacity
#define NBARX (NBLK - 17)   // partial barrier: blocks 32..48 excluded
#define SPIN_MAX 2000000    // watchdog: never wedge the GPU; audited graph
                            // never triggers it (wrong values if it does)

// ws float offsets
#define WS_CCW   0      // [0,101)
#define WS_XSC   128    // [128,229)
#define WS_OH0   256    // 3
#define WS_EOH1  260    // 3
#define WS_RNG   800    // net-2 {u0, dlt, inv} at [808,811)
#define WS_BAR   960    // int region (160 ints)
#define WS_TAB   17408  // 3*G table floats

// bar int indices (each flag on its own 128B cacheline)
#define CNT_X    0      // partial-barrier arrivals
#define CNT_T2   16     // build-2 completions
#define FLG_X    32     // partial barrier released
#define FLG_T2   64     // table 2 ready
#define FLG_OE   96     // net-0 h-MLP (o0,e1) published
#define FLG_RNG  128    // net-2 range published

// R9 post-mortem: __threadfence is a FULL fence (wb + inv). Producers only
// need release (wb), consumers only acquire (inv) -> half the cache-
// maintenance ops, which serialize at each XCD's L2.
#define REL_FENCE() __builtin_amdgcn_fence(__ATOMIC_RELEASE, "agent")
#define ACQ_FENCE() __builtin_amdgcn_fence(__ATOMIC_ACQUIRE, "agent")

__device__ __forceinline__ unsigned short f2bf(float f) {
    unsigned int u = __float_as_uint(f);
    unsigned int r = (u + 0x7FFFu + ((u >> 16) & 1u)) >> 16;  // RNE
    return (unsigned short)r;
}
__device__ __forceinline__ unsigned int hpk(float a, float b) {
    union { h2amd h; unsigned int u; } c;
    c.h = __builtin_amdgcn_cvt_pkrtz(a, b);
    return c.u;
}
__device__ __forceinline__ h2 hpk2(float a, float b) {
    union { h2amd ha; h2 h; } c;
    c.ha = __builtin_amdgcn_cvt_pkrtz(a, b);
    return c.h;
}

// arrival: relaxed add; last arriver sets a flag on a separate line.
__device__ __forceinline__ void bar_arrive(int* bar, int cnt, int flg, int target) {
    __syncthreads();
    if (threadIdx.x == 0) {
        REL_FENCE();   // write-back this block's global writes
        int old = __hip_atomic_fetch_add(&bar[cnt], 1, __ATOMIC_RELAXED,
                                         __HIP_MEMORY_SCOPE_AGENT);
        if (old == target - 1)
            __hip_atomic_store(&bar[flg], 1, __ATOMIC_RELAXED,
                               __HIP_MEMORY_SCOPE_AGENT);
    }
}
// wait: poll write-once flag with relaxed loads (BOUNDED); acquire on exit.
__device__ __forceinline__ void bar_wait(int* bar, int flg) {
    if (threadIdx.x == 0) {
        int spins = 0;
        while (__hip_atomic_load(&bar[flg], __ATOMIC_RELAXED,
                                 __HIP_MEMORY_SCOPE_AGENT) == 0) {
            __builtin_amdgcn_s_sleep(1);
            if (++spins > SPIN_MAX) break;   // watchdog
        }
        ACQ_FENCE();   // invalidate stale cached lines (once)
    }
    __syncthreads();
}

union FR { f16x8 v; h2 h[4]; unsigned int u32[4]; };

// phase-overlaid LDS (max member ~49.8 KB)
union MegaSh {
    struct { float hw[DH * 101]; float bufA[128], bufB[128]; } prep;
    struct {
        __align__(16) _Float16 W1[DH * WSTR];
        __align__(16) _Float16 W2[DH * WSTR];
        unsigned int w0p[64], b0p[64], w3p[64];
        float g[256];
    } mlp;
    struct { __align__(16) float tab[3 * G]; } ev;
};

// verified transposed MFMA dataflow (lane^32 exchange, laundered LDS reads):
// evaluates g(u)=elu(MLP(u))+1 for two 128-row groups; dzout valid on !hfb.
__device__ __forceinline__ void mlp2(const _Float16* __restrict__ W1s,
                                     const _Float16* __restrict__ W2s,
                                     const unsigned int* __restrict__ w0p_s,
                                     const unsigned int* __restrict__ b0p_s,
                                     const unsigned int* __restrict__ w3p_s,
                                     const h2* uu, const int* wrow,
                                     const int hf, const bool hfb,
                                     const float b3, unsigned int zoff,
                                     float* dzout)
{
    const f32x2 zero2 = {0.f, 0.f};

    FR a1[2][7];
    #pragma unroll
    for (int ks = 0; ks < 7; ++ks) {
        int pb = ks * 8 + hf * 4 + zoff;
        uint4 wq = *(const uint4*)&w0p_s[pb];
        uint4 bq = *(const uint4*)&b0p_s[pb];
        unsigned int wqa[4] = {wq.x, wq.y, wq.z, wq.w};
        unsigned int bqa[4] = {bq.x, bq.y, bq.z, bq.w};
        #pragma unroll
        for (int i = 0; i < 4; ++i) {
            union { unsigned int u; h2 h; } cw, cb;
            cw.u = wqa[i]; cb.u = bqa[i];
            h2 z = {(_Float16)0.f, (_Float16)0.f};
            #pragma unroll
            for (int j = 0; j < 2; ++j) {
                h2 r = __builtin_elementwise_fma(uu[j], cw.h, cb.h);
                a1[j][ks].h[i] = __builtin_elementwise_max(r, z);
            }
        }
    }

    FR f3[2][7];
    #pragma unroll
    for (int nt = 0; nt < 4; ++nt) {
        f32x16 acc[2];
        #pragma unroll
        for (int r = 0; r < 16; ++r) { acc[0][r] = 0.f; acc[1][r] = 0.f; }
        #pragma unroll
        for (int ks = 0; ks < 7; ++ks) {
            f16x8 wA = *(const f16x8*)&W1s[wrow[nt] + ks * 16 + zoff];
            acc[0] = __builtin_amdgcn_mfma_f32_32x32x16_f16(wA, a1[0][ks].v, acc[0], 0, 0, 0);
            acc[1] = __builtin_amdgcn_mfma_f32_32x32x16_f16(wA, a1[1][ks].v, acc[1], 0, 0, 0);
        }
        #pragma unroll
        for (int j = 0; j < 2; ++j) {
            if (nt < 3) {
                unsigned int pk[4][2];
                #pragma unroll
                for (int qi = 0; qi < 4; ++qi) {
                    f32x2 lo = {acc[j][4 * qi + 0], acc[j][4 * qi + 1]};
                    f32x2 hi = {acc[j][4 * qi + 2], acc[j][4 * qi + 3]};
                    lo = __builtin_elementwise_max(lo, zero2);
                    hi = __builtin_elementwise_max(hi, zero2);
                    pk[qi][0] = hpk(lo[0], lo[1]);
                    pk[qi][1] = hpk(hi[0], hi[1]);
                }
                #pragma unroll
                for (int kk = 0; kk < 2; ++kk) {
                    unsigned int X0 = hfb ? pk[2 * kk][0] : pk[2 * kk + 1][0];
                    unsigned int X1 = hfb ? pk[2 * kk][1] : pk[2 * kk + 1][1];
                    unsigned int O0 = hfb ? pk[2 * kk + 1][0] : pk[2 * kk][0];
                    unsigned int O1 = hfb ? pk[2 * kk + 1][1] : pk[2 * kk][1];
                    unsigned int Y0 = (unsigned int)__shfl_xor((int)X0, 32, 64);
                    unsigned int Y1 = (unsigned int)__shfl_xor((int)X1, 32, 64);
                    f3[j][nt * 2 + kk].u32[0] = hfb ? Y0 : O0;
                    f3[j][nt * 2 + kk].u32[1] = hfb ? Y1 : O1;
                    f3[j][nt * 2 + kk].u32[2] = hfb ? O0 : Y0;
                    f3[j][nt * 2 + kk].u32[3] = hfb ? O1 : Y1;
                }
            } else {
                f32x2 lo = {acc[j][0], acc[j][1]};
                f32x2 hi = {acc[j][2], acc[j][3]};
                lo = __builtin_elementwise_max(lo, zero2);
                hi = __builtin_elementwise_max(hi, zero2);
                unsigned int p0 = hpk(lo[0], lo[1]);
                unsigned int p1 = hpk(hi[0], hi[1]);
                f3[j][6].u32[0] = hfb ? 0u : p0;
                f3[j][6].u32[1] = hfb ? 0u : p1;
                f3[j][6].u32[2] = hfb ? 0u : 0x00003C00u;   // f16 1.0 (bias slot)
                f3[j][6].u32[3] = 0u;
            }
        }
    }

    f32x2 oacc2[2] = {{0.f, 0.f}, {0.f, 0.f}};
    #pragma unroll
    for (int nt2 = 0; nt2 < 4; ++nt2) {
        f32x16 acc2[2];
        #pragma unroll
        for (int r = 0; r < 16; ++r) { acc2[0][r] = 0.f; acc2[1][r] = 0.f; }
        #pragma unroll
        for (int ks = 0; ks < 7; ++ks) {
            f16x8 wA = *(const f16x8*)&W2s[wrow[nt2] + ks * 16 + zoff];
            acc2[0] = __builtin_amdgcn_mfma_f32_32x32x16_f16(wA, f3[0][ks].v, acc2[0], 0, 0, 0);
            acc2[1] = __builtin_amdgcn_mfma_f32_32x32x16_f16(wA, f3[1][ks].v, acc2[1], 0, 0, 0);
        }
        uint4 wa = *(const uint4*)&w3p_s[hf * 32 + nt2 * 8 + zoff];
        uint4 wb2 = *(const uint4*)&w3p_s[hf * 32 + nt2 * 8 + 4 + zoff];
        unsigned int w8[8] = {wa.x, wa.y, wa.z, wa.w, wb2.x, wb2.y, wb2.z, wb2.w};
        f32x2 w3v[8];
        #pragma unroll
        for (int q = 0; q < 8; ++q) {
            w3v[q][0] = __uint_as_float(w8[q] << 16);
            w3v[q][1] = __uint_as_float(w8[q] & 0xFFFF0000u);
        }
        #pragma unroll
        for (int j = 0; j < 2; ++j)
            #pragma unroll
            for (int qi = 0; qi < 4; ++qi) {
                f32x2 lo = {acc2[j][4 * qi + 0], acc2[j][4 * qi + 1]};
                f32x2 hi = {acc2[j][4 * qi + 2], acc2[j][4 * qi + 3]};
                lo = __builtin_elementwise_max(lo, zero2);
                hi = __builtin_elementwise_max(hi, zero2);
                oacc2[j] = __builtin_elementwise_fma(lo, w3v[qi * 2], oacc2[j]);
                oacc2[j] = __builtin_elementwise_fma(hi, w3v[qi * 2 + 1], oacc2[j]);
            }
    }

    #pragma unroll
    for (int j = 0; j < 2; ++j) {
        float oacc = oacc2[j][0] + oacc2[j][1];
        float o = oacc + __shfl_xor(oacc, 32, 64) + b3;
        dzout[j] = (o > 0.f) ? (o + 1.f) : expf(o);   // elu(o) + 1
    }
}

// vectorized weight staging (float4 loads, RNE f16 convert)
__device__ __forceinline__ void stage_net(MegaSh& sh, int kk, int tid,
                                          const float* __restrict__ iW0,
                                          const float* __restrict__ ib0,
                                          const float* __restrict__ iW1,
                                          const float* __restrict__ ib1,
                                          const float* __restrict__ iW2,
                                          const float* __restrict__ ib2,
                                          const float* __restrict__ iW3)
{
    if (tid < 64) {
        int s0 = 2 * tid, s1 = 2 * tid + 1;
        float w0a = (s0 < DH) ? iW0[(kk * DH + s0) * 3] : 0.f;   // h==0: feature 0 only
        float w0b = (s1 < DH) ? iW0[(kk * DH + s1) * 3] : 0.f;
        float b0a = (s0 < DH) ? ib0[kk * DH + s0] : ((s0 == DH) ? 1.f : 0.f);
        float b0b = (s1 < DH) ? ib0[kk * DH + s1] : 0.f;
        sh.mlp.w0p[tid] = hpk(w0a, w0b);
        sh.mlp.b0p[tid] = hpk(b0a, b0b);

        int hf_i = tid >> 5, rem = tid & 31;
        int nt2 = rem >> 3, qq = (rem >> 1) & 3, pr = rem & 1;
        int n2e = 32 * nt2 + 8 * qq + 2 * pr + 4 * hf_i;
        float we = (n2e < DH) ? iW3[kk * DH + n2e] : 0.f;
        float wo = (n2e + 1 < DH) ? iW3[kk * DH + n2e + 1] : 0.f;
        sh.mlp.w3p[tid] = ((unsigned int)f2bf(wo) << 16) | (unsigned int)f2bf(we);
    }
    // main body: DH*DH = 2500 float4 per matrix (rows are 25 float4 each)
    const float4* W1g4 = (const float4*)(iW1 + (size_t)kk * DH * DH);
    const float4* W2g4 = (const float4*)(iW2 + (size_t)kk * DH * DH);
    for (int i4 = tid; i4 < (DH * DH) / 4; i4 += 256) {
        int r = i4 / 25, c4 = (i4 - r * 25) * 4;
        float4 a = W1g4[i4], bq = W2g4[i4];
        f16x4 va = {(_Float16)a.x, (_Float16)a.y, (_Float16)a.z, (_Float16)a.w};
        f16x4 vb = {(_Float16)bq.x, (_Float16)bq.y, (_Float16)bq.z, (_Float16)bq.w};
        *(f16x4*)&sh.mlp.W1[r * WSTR + c4] = va;
        *(f16x4*)&sh.mlp.W2[r * WSTR + c4] = vb;
    }
    // bias column (c==DH) + zero pad cols 101..119
    for (int i = tid; i < DH * 20; i += 256) {
        int r = i / 20, c = DH + (i - (i / 20) * 20);
        _Float16 v1 = (c == DH) ? (_Float16)ib1[kk * DH + r] : (_Float16)0.f;
        _Float16 v2 = (c == DH) ? (_Float16)ib2[kk * DH + r] : (_Float16)0.f;
        sh.mlp.W1[r * WSTR + c] = v1;
        sh.mlp.W2[r * WSTR + c] = v2;
    }
}

// h-MLP for one net using sh.prep; float4 global loads (rows = 25 float4);
// scalar LDS writes keep the 101-stride anti-conflict layout.
__device__ __forceinline__ void hmlp(MegaSh& sh, int k, int tid,
                                     const float* __restrict__ hb0,
                                     const float* __restrict__ hW1,
                                     const float* __restrict__ hb1,
                                     const float* __restrict__ hW2,
                                     const float* __restrict__ hb2,
                                     const float* __restrict__ hW3,
                                     const float* __restrict__ hb3,
                                     float* __restrict__ ws)
{
    if (tid < 128) sh.prep.bufA[tid] = (tid < DH) ? fmaxf(hb0[k * DH + tid], 0.f) : 0.f;
    __syncthreads();
    {
        const float4* Wg4 = (const float4*)(hW1 + (size_t)k * DH * DH);
        for (int i4 = tid; i4 < (DH * DH) / 4; i4 += 256) {
            int r = i4 / 25, c = (i4 - r * 25) * 4;
            float4 v = Wg4[i4];
            float* d = &sh.prep.hw[r * 101 + c];
            d[0] = v.x; d[1] = v.y; d[2] = v.z; d[3] = v.w;
        }
    }
    __syncthreads();
    if (tid < DH) {
        float acc = hb1[k * DH + tid];
        for (int i = 0; i < DH; ++i) acc = fmaf(sh.prep.hw[tid * 101 + i], sh.prep.bufA[i], acc);
        sh.prep.bufB[tid] = fmaxf(acc, 0.f);
    }
    __syncthreads();
    {
        const float4* Wg4 = (const float4*)(hW2 + (size_t)k * DH * DH);
        for (int i4 = tid; i4 < (DH * DH) / 4; i4 += 256) {
            int r = i4 / 25, c = (i4 - r * 25) * 4;
            float4 v = Wg4[i4];
            float* d = &sh.prep.hw[r * 101 + c];
            d[0] = v.x; d[1] = v.y; d[2] = v.z; d[3] = v.w;
        }
    }
    __syncthreads();
    if (tid < DH) {
        float acc = hb2[k * DH + tid];
        for (int i = 0; i < DH; ++i) acc = fmaf(sh.prep.hw[tid * 101 + i], sh.prep.bufB[i], acc);
        sh.prep.bufA[tid] = fmaxf(acc, 0.f);
    }
    __syncthreads();
    if (tid < 2) {
        float acc = hb3[k * 2 + tid];
        const float* w = hW3 + (size_t)(k * 2 + tid) * DH;
        for (int i = 0; i < DH; ++i) acc = fmaf(w[i], sh.prep.bufA[i], acc);
        if (tid == 0) ws[WS_OH0 + k] = acc;
        else          ws[WS_EOH1 + k] = expf(acc);
    }
    __syncthreads();
}

__device__ __forceinline__ void cc_consts(float* __restrict__ dst_ccw,
                                          float* __restrict__ dst_xsc, int tid)
{
    // cos(j*t*pi/100) has period 200 in (j*t): exact integer reduction,
    // then small-arg cosf (f32 error ~1e-6 on O(0.02) weights).
    if (tid <= 100) {
        const int t = tid;
        float ccw = 0.f;
        for (int j = 0; j <= 100; j += 2) {
            float wj = (j == 0) ? 1.f : 2.f / (1.f - (float)(j * j));
            float lam;
            if (t == 0) lam = 0.5f;
            else {
                int r = (j * t) % 200;
                lam = cosf((float)r * 0.031415926535f);   // r*pi/100
                if (t == 100) lam *= 0.5f;
            }
            ccw = fmaf(lam * wj, 0.02f, ccw);
        }
        dst_ccw[tid] = ccw;
        dst_xsc[tid] = (cosf((float)t * 0.031415926535f) + 1.f) * 0.5f;
    }
}

__device__ __forceinline__ float quadz(const float* __restrict__ tab_s,
                                       const float* __restrict__ xsc_s,
                                       const float* __restrict__ ccw_s,
                                       float x, float u0, float invd, int psub)
{
    float z = 0.f;
    for (int p = psub; p < 101; p += 4) {
        float u = x * xsc_s[p];
        float tt = fminf(fmaxf((u - u0) * invd, 0.f), (float)(G - 1) - 0.001f);
        int i = (int)tt;
        float f = tt - (float)i;
        float g0 = tab_s[i];
        float g1 = tab_s[i + 1];
        z = fmaf(ccw_s[p], fmaf(f, g1 - g0, g0), z);
    }
    z += __shfl_xor(z, 1, 64);
    z += __shfl_xor(z, 2, 64);
    return z;
}

// Single kernel; partial barrier + flag chain takes probe/build-2 off the tail
// (R9-verified schedule; this round only splits fences + vectorizes loads):
//  all   : prologue (replicated float4 min/max + passthrough)
//  b 0-31: build tables 0,1 -> arrive barX
//  b32-47: stage net-2, wait RNG flag, build table 2, count -> FLG_T2 (no barX)
//  b 48  : probe: cc + stage net-0 + endpoint MFMA, wait FLG_OE, range -> FLG_RNG
//  b 49  : h-MLP net 0 -> FLG_OE -> arrive;  b50/51: h-MLP 1,2 -> arrive
//  b 52  : cc consts -> ws -> arrive;  b53+: arrive
//  all   : wait FLG_X -> stage tabs 0,1 -> y1 + x2 (regs)
//          -> wait FLG_T2 -> stage tab 2 -> y2
__global__ __launch_bounds__(256, 2)
void mega_kernel(const float* __restrict__ logits,
                 const float* __restrict__ iW0, const float* __restrict__ ib0,
                 const float* __restrict__ iW1, const float* __restrict__ ib1,
                 const float* __restrict__ iW2, const float* __restrict__ ib2,
                 const float* __restrict__ iW3, const float* __restrict__ ib3,
                 const float* __restrict__ hb0,
                 const float* __restrict__ hW1, const float* __restrict__ hb1,
                 const float* __restrict__ hW2, const float* __restrict__ hb2,
                 const float* __restrict__ hW3, const float* __restrict__ hb3,
                 float* __restrict__ ws, float* __restrict__ out, int n)
{
    __shared__ MegaSh sh;
    __shared__ float xsc_s[104], ccw_s[104];
    __shared__ float rmin_s[4], rmax_s[4];

    int* bar = (int*)(ws + WS_BAR);
    const int tid = threadIdx.x;
    const int b = blockIdx.x;
    const int lane = tid & 63;
    const int wv = tid >> 6;
    const int hf = lane >> 5;
    const bool hfb = (hf != 0);
    const int l31 = lane & 31;
    const int spb = (n + NBLK - 1) / NBLK;      // 128 at n=16384
    const int ibeg = b * spb;
    const int iend = (ibeg + spb < n) ? (ibeg + spb) : n;

    // ---- prologue: replicated float4 min/max + own-slice passthrough ----
    {
        float lmin = 1e30f, lmax = -1e30f;
        const float4* lg4 = (const float4*)logits;
        for (int i = tid; i < (n >> 2); i += 256) {
            float4 v = lg4[i];
            lmin = fminf(lmin, fminf(fminf(v.x, v.y), fminf(v.z, v.w)));
            lmax = fmaxf(lmax, fmaxf(fmaxf(v.x, v.y), fmaxf(v.z, v.w)));
        }
        // tail (n not multiple of 4)
        for (int i = (n & ~3) + tid; i < n; i += 256) {
            float v = logits[i];
            lmin = fminf(lmin, v);
            lmax = fmaxf(lmax, v);
        }
        // own-slice passthrough (out + 2n is 16B-aligned when n%4==0)
        if ((n & 3) == 0 && (ibeg & 3) == 0) {
            float4* o4 = (float4*)(out + 2 * n + ibeg);
            const float4* s4 = (const float4*)(logits + ibeg);
            int cnt4 = (iend - ibeg) >> 2;
            for (int i = tid; i < cnt4; i += 256) o4[i] = s4[i];
            for (int i = ibeg + (cnt4 << 2) + tid; i < iend; i += 256)
                out[2 * n + i] = logits[i];
        } else {
            for (int i = ibeg + tid; i < iend; i += 256)
                out[2 * n + i] = logits[i];
        }
        #pragma unroll
        for (int off = 1; off < 64; off <<= 1) {
            lmin = fminf(lmin, __shfl_xor(lmin, off, 64));
            lmax = fmaxf(lmax, __shfl_xor(lmax, off, 64));
        }
        if (lane == 0) { rmin_s[wv] = lmin; rmax_s[wv] = lmax; }
    }
    __syncthreads();
    const float xm = fminf(fminf(rmin_s[0], rmin_s[1]), fminf(rmin_s[2], rmin_s[3]));
    const float xM = fmaxf(fmaxf(rmax_s[0], rmax_s[1]), fmaxf(rmax_s[2], rmax_s[3]));
    // table-0/1 range (identical on every block: same data, same FP order)
    const float um01 = fminf(xm, 0.f);
    const float uM01 = fmaxf(xM, 0.f);
    const float span01 = fmaxf(uM01 - um01, 1e-5f);
    const float dlt01 = span01 * (1.f / (float)(G - 1));
    const float inv01 = (float)(G - 1) / span01;

    unsigned int zoff = 0;
    asm volatile("" : "+v"(zoff));   // opaque zero (keeps LDS reads un-cached)

    int wrow[4];
    #pragma unroll
    for (int nt = 0; nt < 4; ++nt) {
        int r = nt * 32 + l31;
        wrow[nt] = ((r > DH - 1) ? (DH - 1) : r) * WSTR + hf * 8;
    }

    // ---------------- pre-barrier roles ----------------
    if (b < 32) {
        const int kk = b >> 4;
        stage_net(sh, kk, tid, iW0, ib0, iW1, ib1, iW2, ib2, iW3);
        __syncthreads();
        const float b3 = ib3[kk];
        float* __restrict__ tab = ws + WS_TAB + kk * G;
        int mr[2];
        h2 uu[2];
        #pragma unroll
        for (int j = 0; j < 2; ++j) {
            mr[j] = (b & 15) * 256 + j * 128 + wv * 32 + l31;
            float u = fmaf((float)mr[j], dlt01, um01);
            uu[j] = hpk2(u, u);
        }
        float dz[2];
        mlp2(sh.mlp.W1, sh.mlp.W2, sh.mlp.w0p, sh.mlp.b0p, sh.mlp.w3p,
             uu, wrow, hf, hfb, b3, zoff, dz);
        #pragma unroll
        for (int j = 0; j < 2; ++j) if (!hfb) tab[mr[j]] = dz[j];
        bar_arrive(bar, CNT_X, FLG_X, NBARX);
    } else if (b < 48) {
        // build table 2: stage overlapped, wait on probe's range flag
        stage_net(sh, 2, tid, iW0, ib0, iW1, ib1, iW2, ib2, iW3);
        __syncthreads();
        bar_wait(bar, FLG_RNG);
        const float u0 = ws[WS_RNG + 8];
        const float dlt = ws[WS_RNG + 9];
        const float b3 = ib3[2];
        float* __restrict__ tab = ws + WS_TAB + 2 * G;
        int mr[2];
        h2 uu[2];
        #pragma unroll
        for (int j = 0; j < 2; ++j) {
            mr[j] = (b & 15) * 256 + j * 128 + wv * 32 + l31;
            float u = fmaf((float)mr[j], dlt, u0);
            uu[j] = hpk2(u, u);
        }
        float dz[2];
        mlp2(sh.mlp.W1, sh.mlp.W2, sh.mlp.w0p, sh.mlp.b0p, sh.mlp.w3p,
             uu, wrow, hf, hfb, b3, zoff, dz);
        #pragma unroll
        for (int j = 0; j < 2; ++j) if (!hfb) tab[mr[j]] = dz[j];
        // completion count -> FLG_T2 (no barX arrival for these blocks)
        __syncthreads();
        if (tid == 0) {
            REL_FENCE();
            int old = __hip_atomic_fetch_add(&bar[CNT_T2], 1, __ATOMIC_RELAXED,
                                             __HIP_MEMORY_SCOPE_AGENT);
            if (old == 15)
                __hip_atomic_store(&bar[FLG_T2], 1, __ATOMIC_RELAXED,
                                   __HIP_MEMORY_SCOPE_AGENT);
        }
    } else if (b == 48) {
        // probe: cc consts + net-0 weights + endpoint MFMA; h-MLP via FLG_OE
        cc_consts(ccw_s, xsc_s, tid);
        stage_net(sh, 0, tid, iW0, ib0, iW1, ib1, iW2, ib2, iW3);
        __syncthreads();
        const float b3 = ib3[0];
        int rr[2];
        h2 uu[2];
        #pragma unroll
        for (int j = 0; j < 2; ++j) {
            rr[j] = j * 128 + wv * 32 + l31;
            int r = rr[j];
            float xe = (r < 101) ? xm : xM;
            int p = (r < 101) ? r : (r - 101);
            if (p > 100) p = 0;
            float u = (r < 202) ? xe * xsc_s[p] : 0.f;
            uu[j] = hpk2(u, u);
        }
        float dz[2];
        mlp2(sh.mlp.W1, sh.mlp.W2, sh.mlp.w0p, sh.mlp.b0p, sh.mlp.w3p,
             uu, wrow, hf, hfb, b3, zoff, dz);
        #pragma unroll
        for (int j = 0; j < 2; ++j) if (!hfb) sh.mlp.g[rr[j]] = dz[j];
        __syncthreads();
        bar_wait(bar, FLG_OE);   // net-0 (o0,e1) published by block 49

        if (tid < 64) {
            float s0a = 0.f, s1a = 0.f;
            for (int p = tid; p < 101; p += 64) {
                float c = ccw_s[p];
                s0a = fmaf(c, sh.mlp.g[p], s0a);
                s1a = fmaf(c, sh.mlp.g[101 + p], s1a);
            }
            #pragma unroll
            for (int off = 1; off < 64; off <<= 1) {
                s0a += __shfl_xor(s0a, off, 64);
                s1a += __shfl_xor(s1a, off, 64);
            }
            if (tid == 0) {
                float z0 = 0.5f * xm * s0a;
                float z1 = 0.5f * xM * s1a;
                float o0 = ws[WS_OH0 + 0], e1 = ws[WS_EOH1 + 0];
                float a = fmaf(e1, z0, o0);
                float bb = fmaf(e1, z1, o0);
                float x2m = fminf(a, bb), x2M = fmaxf(a, bb);
                float sp = fmaxf(x2M - x2m, 1e-6f);
                x2m -= 0.02f * sp;                 // safety margin: quadrature
                x2M += 0.02f * sp;                 // wiggle + table-lerp error
                float um = fminf(x2m, 0.f), uM = fmaxf(x2M, 0.f);
                float span = fmaxf(uM - um, 1e-5f);
                ws[WS_RNG + 8]  = um;
                ws[WS_RNG + 9]  = span * (1.f / (float)(G - 1));
                ws[WS_RNG + 10] = (float)(G - 1) / span;
                REL_FENCE();       // release WS_RNG[8..10]
                __hip_atomic_store(&bar[FLG_RNG], 1, __ATOMIC_RELAXED,
                                   __HIP_MEMORY_SCOPE_AGENT);
            }
        }
    } else if (b == 49) {
        hmlp(sh, 0, tid, hb0, hW1, hb1, hW2, hb2, hW3, hb3, ws);
        if (tid == 0) {
            REL_FENCE();
            __hip_atomic_store(&bar[FLG_OE], 1, __ATOMIC_RELAXED,
                               __HIP_MEMORY_SCOPE_AGENT);
        }
        bar_arrive(bar, CNT_X, FLG_X, NBARX);
    } else if (b == 50 || b == 51) {
        hmlp(sh, b - 49, tid, hb0, hW1, hb1, hW2, hb2, hW3, hb3, ws);
        bar_arrive(bar, CNT_X, FLG_X, NBARX);
    } else if (b == 52) {
        cc_consts(ws + WS_CCW, ws + WS_XSC, tid);
        bar_arrive(bar, CNT_X, FLG_X, NBARX);
    } else {
        bar_arrive(bar, CNT_X, FLG_X, NBARX);
    }

    // ---------------- eval part 1: y1 + x2 (tables 0,1 only) ----------------
    bar_wait(bar, FLG_X);
    {
        const float* tg = ws + WS_TAB;
        for (int i = tid * 4; i < 2 * G; i += 1024)
            *(float4*)&sh.ev.tab[i] = *(const float4*)&tg[i];
        if (tid < 101) {
            xsc_s[tid] = ws[WS_XSC + tid];
            ccw_s[tid] = ws[WS_CCW + tid];
        }
    }
    __syncthreads();

    const float o00 = ws[WS_OH0 + 0], e10 = ws[WS_EOH1 + 0];
    const float o01 = ws[WS_OH0 + 1], e11 = ws[WS_EOH1 + 1];
    const int psub = tid & 3;
    const bool hasA = (ibeg < iend);
    const bool hasB = (ibeg + 64 < iend);
    const int nnA = ibeg + (tid >> 2);
    const int nnB = ibeg + 64 + (tid >> 2);
    float xA = 0.f, xB = 0.f, x2A = 0.f, x2B = 0.f;

    if (hasA) {
        xA = (nnA < iend) ? logits[nnA] : 0.f;
        float z1 = quadz(sh.ev.tab + G, xsc_s, ccw_s, xA, um01, inv01, psub);
        float z0 = quadz(sh.ev.tab, xsc_s, ccw_s, xA, um01, inv01, psub);
        if (nnA < iend && psub == 0) out[nnA] = fmaf(e11, 0.5f * xA * z1, o01);
        x2A = fmaf(e10, 0.5f * xA * z0, o00);
    }
    if (hasB) {
        xB = (nnB < iend) ? logits[nnB] : 0.f;
        float z1 = quadz(sh.ev.tab + G, xsc_s, ccw_s, xB, um01, inv01, psub);
        float z0 = quadz(sh.ev.tab, xsc_s, ccw_s, xB, um01, inv01, psub);
        if (nnB < iend && psub == 0) out[nnB] = fmaf(e11, 0.5f * xB * z1, o01);
        x2B = fmaf(e10, 0.5f * xB * z0, o00);
    }

    // ---------------- eval part 2: y2 (table 2, usually already built) ------
    bar_wait(bar, FLG_T2);
    {
        const float* tg = ws + WS_TAB;
        for (int i = 2 * G + tid * 4; i < 3 * G; i += 1024)
            *(float4*)&sh.ev.tab[i] = *(const float4*)&tg[i];
    }
    __syncthreads();

    const float u02 = ws[WS_RNG + 8], iv2v = ws[WS_RNG + 10];
    const float o02 = ws[WS_OH0 + 2], e12 = ws[WS_EOH1 + 2];

    if (hasA) {
        float z2 = quadz(sh.ev.tab + 2 * G, xsc_s, ccw_s, x2A, u02, iv2v, psub);
        if (nnA < iend && psub == 0) out[n + nnA] = fmaf(e12, 0.5f * x2A * z2, o02);
    }
    if (hasB) {
        float z2 = quadz(sh.ev.tab + 2 * G, xsc_s, ccw_s, x2B, u02, iv2v, psub);
        if (nnB < iend && psub == 0) out[n + nnB] = fmaf(e12, 0.5f * x2B * z2, o02);
    }
}

extern "C" void kernel_launch(void* const* d_in, const int* in_sizes, int n_in,
                              void* d_out, int out_size, void* d_ws, size_t ws_size,
                              hipStream_t stream)
{
    const float* logits = (const float*)d_in[0];
    const float* iW0 = (const float*)d_in[2];
    const float* ib0 = (const float*)d_in[3];
    const float* iW1 = (const float*)d_in[4];
    const float* ib1 = (const float*)d_in[5];
    const float* iW2 = (const float*)d_in[6];
    const float* ib2 = (const float*)d_in[7];
    const float* iW3 = (const float*)d_in[8];
    const float* ib3 = (const float*)d_in[9];
    const float* hb0 = (const float*)d_in[11];
    const float* hW1 = (const float*)d_in[12];
    const float* hb1 = (const float*)d_in[13];
    const float* hW2 = (const float*)d_in[14];
    const float* hb2 = (const float*)d_in[15];
    const float* hW3 = (const float*)d_in[16];
    const float* hb3 = (const float*)d_in[17];
    float* out = (float*)d_out;
    float* ws = (float*)d_ws;
    int n = in_sizes[0];

    // zero counters + flags (captured per-iteration; replay-safe fall-through)
    hipMemsetAsync((void*)(ws + WS_BAR), 0, 160 * sizeof(int), stream);

    hipLaunchKernelGGL(mega_kernel, dim3(NBLK), dim3(256), 0, stream,
                       logits, iW0, ib0, iW1, ib1, iW2, ib2, iW3, ib3,
                       hb0, hW1, hb1, hW2, hb2, hW3, hb3, ws, out, n);
}